// Round 16
// baseline (22.703 us; speedup 1.0000x reference)
//
#include <hip/hip_runtime.h>
#include <math.h>

// ---------------------------------------------------------------------------
// DirectVoxGO Raw2Alpha + Alphas2Weights (forward), single fused kernel.
//
// outputs (concatenated in d_out, float32):
//   weights[n_pts]         = alpha_j * T_j,  T_j = prod_{k<j} (1-alpha_k)
//   alphainv_last[n_rays]  = prod over ray of (1-alpha)  (empty rays -> 1.0)
//
// Structure (R10 family): 1 block (256 thr) per 2048 consecutive points,
// 8 pts/thread, ALL loads issued up front, XCD-aware bijective block swizzle.
// ONE barrier per block: the 256-pt lookback window (head product of the
// straddling ray) is processed REDUNDANTLY by each wave (4 elems/lane,
// L2-hit loads), making the head-search and head-product wave-local (DPP +
// readlane) — no LDS round-trips on that path. The single barrier publishes
// the per-wave (value,flag) scan totals for the cross-wave combine.
// ---------------------------------------------------------------------------

#define LOG2E 1.4426950408889634f
#define EPT   8                     // elements per thread (VGPR-safe)
#define BPTS  (256 * EPT)           // points per block = 2048
#define WIN   256                   // lookback window width
#define WPL   (WIN / 64)            // window elements per lane = 4
#define NXCD  8

typedef float vf4 __attribute__((ext_vector_type(4)));

__device__ __forceinline__ float exp2f_(float x) { return __builtin_amdgcn_exp2f(x); }
__device__ __forceinline__ float log2f_(float x) { return __builtin_amdgcn_logf(x); }
__device__ __forceinline__ float rsqf_(float x)  { return __builtin_amdgcn_rsqf(x); }

__device__ __forceinline__ float oma(float d, float sh2, float negc, bool fast) {
    const float y = fmaf(d, LOG2E, sh2);
    if (fast) return rsqf_(1.0f + exp2f_(y));
    const float sp = fmaxf(y, 0.f) + log2f_(1.f + exp2f_(-fabsf(y)));
    return exp2f_(negc * sp);
}

// Segmented-scan DPP step: combine src (earlier lanes, identity (1,0) when
// out-of-row/masked) into (V,F):  V = F ? V : Vs*V;  F |= Fs.
template <int CTRL, int RM>
__device__ __forceinline__ void seg_step(float& V, int& F) {
    const int vs_i = __builtin_amdgcn_update_dpp(
        0x3f800000, __builtin_bit_cast(int, V), CTRL, RM, 0xF, false);
    const int fs = __builtin_amdgcn_update_dpp(0, F, CTRL, RM, 0xF, false);
    const float vs = __builtin_bit_cast(float, vs_i);
    V = F ? V : vs * V;
    F = F | fs;
}

// Full-wave product, result broadcast to all lanes.
__device__ __forceinline__ float wave_prod_bcast(float x) {
#define STEPP(CTRL, RM)                                                        \
    { int t_ = __builtin_amdgcn_update_dpp(0x3f800000,                         \
          __builtin_bit_cast(int, x), CTRL, RM, 0xF, false);                   \
      x *= __builtin_bit_cast(float, t_); }
    STEPP(0x111, 0xF) STEPP(0x112, 0xF) STEPP(0x114, 0xF)
    STEPP(0x118, 0xF) STEPP(0x142, 0xA) STEPP(0x143, 0xC)
#undef STEPP
    return __builtin_bit_cast(float,
        __builtin_amdgcn_readlane(__builtin_bit_cast(int, x), 63));
}

// Full-wave int max, result broadcast to all lanes.
__device__ __forceinline__ int wave_imax_bcast(int x) {
#define STEPM(CTRL, RM)                                                        \
    { int t_ = __builtin_amdgcn_update_dpp((int)0x80000000, x, CTRL, RM,       \
                                           0xF, false);                        \
      x = (x > t_) ? x : t_; }
    STEPM(0x111, 0xF) STEPM(0x112, 0xF) STEPM(0x114, 0xF)
    STEPM(0x118, 0xF) STEPM(0x142, 0xA) STEPM(0x143, 0xC)
#undef STEPM
    return __builtin_amdgcn_readlane(x, 63);
}

__global__ void __launch_bounds__(256)
fused_alpha_weights(const float* __restrict__ density,
                    const int*   __restrict__ ray_id,
                    const float* __restrict__ shift_p,
                    const float* __restrict__ interval_p,
                    float* __restrict__ weights,
                    float* __restrict__ alphainv,
                    int n_pts, int n_rays) {
    __shared__ float s_wv[4];
    __shared__ int   s_wf[4];

    const int t    = threadIdx.x;
    const int lane = t & 63;
    const int wid  = t >> 6;

    // XCD-aware bijective swizzle (m204): XCD k owns a contiguous data chunk,
    // so data-neighbor blocks are consecutive launches on the SAME XCD.
    const int nwg  = gridDim.x;
    const int orig = blockIdx.x;
    const int qq   = nwg / NXCD, rr = nwg % NXCD;
    const int xcd  = orig % NXCD;
    const int blk  = (xcd < rr ? xcd * (qq + 1) : rr * (qq + 1) + (xcd - rr) * qq)
                   + orig / NXCD;

    const int base = blk * BPTS;
    const int idx0 = base + t * EPT;

    const float shift = shift_p[0];
    const float c     = interval_p[0];
    const float sh2   = shift * LOG2E;
    const float negc  = -c;
    const bool  fast  = (c == 0.5f);

    // ================= phase 0: issue ALL loads up front =================
    int r[EPT + 1]; float d[EPT]; bool v[EPT];
    if (idx0 + EPT <= n_pts) {
        const int4   ri0 = *reinterpret_cast<const int4*>(ray_id + idx0);
        const int4   ri1 = *reinterpret_cast<const int4*>(ray_id + idx0 + 4);
        const float4 de0 = *reinterpret_cast<const float4*>(density + idx0);
        const float4 de1 = *reinterpret_cast<const float4*>(density + idx0 + 4);
        r[0] = ri0.x; r[1] = ri0.y; r[2] = ri0.z; r[3] = ri0.w;
        r[4] = ri1.x; r[5] = ri1.y; r[6] = ri1.z; r[7] = ri1.w;
        d[0] = de0.x; d[1] = de0.y; d[2] = de0.z; d[3] = de0.w;
        d[4] = de1.x; d[5] = de1.y; d[6] = de1.z; d[7] = de1.w;
        #pragma unroll
        for (int k = 0; k < EPT; ++k) v[k] = true;
    } else {
        #pragma unroll
        for (int k = 0; k < EPT; ++k) {
            const int i = idx0 + k;
            v[k] = (i < n_pts);
            r[k] = v[k] ? ray_id[i] : n_rays;    // sentinel past-end ray
            d[k] = v[k] ? density[i] : 0.0f;
        }
    }

    // wave-boundary neighbor ids: only lanes 0/63 touch memory (L1-hot lines)
    int rprev_edge = -1;
    if (lane == 0 && idx0 > 0 && idx0 <= n_pts) rprev_edge = ray_id[idx0 - 1];
    int rnext_edge = n_rays;
    if (lane == 63 && idx0 + EPT < n_pts) rnext_edge = ray_id[idx0 + EPT];

    // lookback window, processed redundantly per wave: 4 elems/lane,
    // element index i = 64*j + lane, address base-WIN+i (coalesced, L2-hot)
    int   w_id[WPL]; float w_den[WPL];
    int   rfirst = 0;
    if (base > 0) {
        rfirst = ray_id[base];                   // uniform, cached
        #pragma unroll
        for (int j = 0; j < WPL; ++j) {
            const int wi = base - WIN + 64 * j + lane;
            w_id[j]  = ray_id[wi];
            w_den[j] = density[wi];
        }
    }

    // neighbor ray ids from adjacent lanes' registers (no strided gathers)
    const int rp_sh = __shfl_up(r[EPT - 1], 1, 64);
    const int rprev = (lane > 0) ? rp_sh : rprev_edge;
    const int rn_sh = __shfl_down(r[0], 1, 64);
    r[EPT] = (lane < 63) ? rn_sh : rnext_edge;

    // ================= phase 1: per-element values & flags =================
    float a[EPT]; int f[EPT];
    #pragma unroll
    for (int k = 0; k < EPT; ++k) {
        const float av = oma(d[k], sh2, negc, fast);
        a[k] = v[k] ? av : 1.0f;
        f[k] = (k == 0) ? (r[0] != rprev) : (r[k] != r[k - 1]);
    }

    // thread-local (V,F) fold over EPT elements
    float V = a[0];  int F = f[0];
    #pragma unroll
    for (int k = 1; k < EPT; ++k) {
        V = f[k] ? a[k] : V * a[k];
        F |= f[k];
    }

    // wave64 inclusive segmented scan (DPP, VALU-only)
    float Vi = V;  int Fi = F;
    seg_step<0x111, 0xF>(Vi, Fi);   // row_shr:1
    seg_step<0x112, 0xF>(Vi, Fi);   // row_shr:2
    seg_step<0x114, 0xF>(Vi, Fi);   // row_shr:4
    seg_step<0x118, 0xF>(Vi, Fi);   // row_shr:8
    seg_step<0x142, 0xA>(Vi, Fi);   // row_bcast:15 -> rows 1,3
    seg_step<0x143, 0xC>(Vi, Fi);   // row_bcast:31 -> rows 2,3

    if (lane == 63) { s_wv[wid] = Vi; s_wf[wid] = Fi; }

    // ========== head carry: fully wave-local (no LDS, no barrier) ==========
    float carry0 = 1.0f;
    if (base > 0) {
        // find m = max window index whose id differs from rfirst (-1 if none)
        int cand = -1;
        #pragma unroll
        for (int j = 0; j < WPL; ++j)
            if (w_id[j] != rfirst) cand = 64 * j + lane;   // j ascending: max
        const int m = wave_imax_bcast(cand);

        // product over window indices > m
        float pp = 1.0f;
        #pragma unroll
        for (int j = 0; j < WPL; ++j) {
            const int i = 64 * j + lane;
            const float aa = oma(w_den[j], sh2, negc, fast);
            pp *= (i > m) ? aa : 1.0f;
        }
        carry0 = wave_prod_bcast(pp);

        if (m < 0) {                 // freak ray (head > WIN back): wave-local walk
            int lo = base - WIN;
            int mg = -1;
            while (mg < 0) {
                const int wstart = lo - WIN;
                int c2 = -1;
                float pw = 1.0f;
                #pragma unroll
                for (int j = 0; j < WPL; ++j) {
                    const int i = wstart + 64 * j + lane;
                    const int vv = (i >= 0) ? ray_id[i] : -1;    // i<0 differs
                    if (vv != rfirst) c2 = 64 * j + lane;
                }
                const int m2 = wave_imax_bcast(c2);
                #pragma unroll
                for (int j = 0; j < WPL; ++j) {
                    const int iw = 64 * j + lane;
                    const int i  = wstart + iw;
                    float aa = 1.0f;
                    if (iw > m2 && i >= 0) aa = oma(density[i], sh2, negc, fast);
                    pw *= aa;
                }
                carry0 *= wave_prod_bcast(pw);
                if (m2 >= 0) mg = 1; else lo = wstart;
            }
        }
    }

    __syncthreads();                             // the ONLY barrier

    // exclusive pair for this thread (within wave)
    float Vx = __shfl_up(Vi, 1, 64);
    int   Fx = __shfl_up(Fi, 1, 64);
    if (lane == 0) { Vx = 1.0f; Fx = 0; }

    // fold block head carry + lower waves + lower lanes
    float Ev = carry0;
    #pragma unroll
    for (int w2 = 0; w2 < 3; ++w2) {
        if (w2 < wid) {
            const float bv = s_wv[w2];  const int bf = s_wf[w2];
            Ev = bf ? bv : Ev * bv;
        }
    }
    Ev = Fx ? Vx : Ev * Vx;            // exclusive transmittance at elem 0

    // ================= phase 3: T chain, weights, alphainv =================
    float T[EPT], e[EPT];
    float prev = Ev;
    #pragma unroll
    for (int k = 0; k < EPT; ++k) {
        T[k] = f[k] ? 1.0f : prev;
        e[k] = T[k] * a[k];
        prev = e[k];
    }

    if (idx0 + EPT <= n_pts) {
        vf4 w0 = { T[0] - e[0], T[1] - e[1], T[2] - e[2], T[3] - e[3] };
        vf4 w1 = { T[4] - e[4], T[5] - e[5], T[6] - e[6], T[7] - e[7] };
        __builtin_nontemporal_store(w0, reinterpret_cast<vf4*>(weights + idx0));
        __builtin_nontemporal_store(w1, reinterpret_cast<vf4*>(weights + idx0 + 4));
    } else {
        #pragma unroll
        for (int k = 0; k < EPT; ++k)
            if (v[k]) weights[idx0 + k] = T[k] - e[k];
    }

    // segment ends: write alphainv for ending ray; fill empty rays in gaps
    #pragma unroll
    for (int k = 0; k < EPT; ++k) {
        if (v[k] && r[k] != r[k + 1]) {
            alphainv[r[k]] = e[k];
            for (int q = r[k] + 1; q < r[k + 1]; ++q) alphainv[q] = 1.0f;
        }
    }
    if (idx0 == 0) {                    // rays before the first point
        for (int q = 0; q < r[0]; ++q) alphainv[q] = 1.0f;
    }
}

extern "C" void kernel_launch(void* const* d_in, const int* in_sizes, int n_in,
                              void* d_out, int out_size, void* d_ws, size_t ws_size,
                              hipStream_t stream) {
    const float* density  = (const float*)d_in[0];
    const float* shift    = (const float*)d_in[1];   // 1-element array
    const float* interval = (const float*)d_in[2];   // 1-element array
    const int*   ray_id   = (const int*)d_in[3];
    const int n_pts  = in_sizes[0];
    const int n_rays = out_size - n_pts;

    float* weights  = (float*)d_out;              // [n_pts]
    float* alphainv = (float*)d_out + n_pts;      // [n_rays]

    const int grid = (n_pts + BPTS - 1) / BPTS;
    fused_alpha_weights<<<grid, 256, 0, stream>>>(
        density, ray_id, shift, interval, weights, alphainv, n_pts, n_rays);
}

// Round 17
// 21.960 us; speedup vs baseline: 1.0338x; 1.0338x over previous
//
#include <hip/hip_runtime.h>
#include <math.h>

// ---------------------------------------------------------------------------
// DirectVoxGO Raw2Alpha + Alphas2Weights (forward), single fused kernel.
//
// outputs (concatenated in d_out, float32):
//   weights[n_pts]         = alpha_j * T_j,  T_j = prod_{k<j} (1-alpha_k)
//   alphainv_last[n_rays]  = prod over ray of (1-alpha)  (empty rays -> 1.0)
//
// Structure: FULLY WAVE-INDEPENDENT. 256-thr blocks, but each wave64 owns
// its own 512 consecutive points (8/lane) plus its own 256-pt lookback
// window to recompute the straddling ray's head product (wave-local DPP
// search + product). Zero LDS, zero __syncthreads — a wave completes as
// soon as its own loads land (no max-over-waves latency coupling).
// XCD-aware bijective block swizzle keeps lookbacks L2-resident.
// ---------------------------------------------------------------------------

#define LOG2E 1.4426950408889634f
#define EPT   8                     // elements per lane
#define WSPAN (64 * EPT)            // points per wave = 512
#define BPTS  (4 * WSPAN)           // points per block = 2048
#define WIN   256                   // lookback window width
#define WPL   (WIN / 64)            // window elements per lane = 4
#define NXCD  8

typedef float vf4 __attribute__((ext_vector_type(4)));

__device__ __forceinline__ float exp2f_(float x) { return __builtin_amdgcn_exp2f(x); }
__device__ __forceinline__ float log2f_(float x) { return __builtin_amdgcn_logf(x); }
__device__ __forceinline__ float rsqf_(float x)  { return __builtin_amdgcn_rsqf(x); }

__device__ __forceinline__ float oma(float d, float sh2, float negc, bool fast) {
    const float y = fmaf(d, LOG2E, sh2);
    if (fast) return rsqf_(1.0f + exp2f_(y));
    const float sp = fmaxf(y, 0.f) + log2f_(1.f + exp2f_(-fabsf(y)));
    return exp2f_(negc * sp);
}

// Segmented-scan DPP step: combine src (earlier lanes, identity (1,0) when
// out-of-row/masked) into (V,F):  V = F ? V : Vs*V;  F |= Fs.
template <int CTRL, int RM>
__device__ __forceinline__ void seg_step(float& V, int& F) {
    const int vs_i = __builtin_amdgcn_update_dpp(
        0x3f800000, __builtin_bit_cast(int, V), CTRL, RM, 0xF, false);
    const int fs = __builtin_amdgcn_update_dpp(0, F, CTRL, RM, 0xF, false);
    const float vs = __builtin_bit_cast(float, vs_i);
    V = F ? V : vs * V;
    F = F | fs;
}

// Full-wave product, result broadcast to all lanes.
__device__ __forceinline__ float wave_prod_bcast(float x) {
#define STEPP(CTRL, RM)                                                        \
    { int t_ = __builtin_amdgcn_update_dpp(0x3f800000,                         \
          __builtin_bit_cast(int, x), CTRL, RM, 0xF, false);                   \
      x *= __builtin_bit_cast(float, t_); }
    STEPP(0x111, 0xF) STEPP(0x112, 0xF) STEPP(0x114, 0xF)
    STEPP(0x118, 0xF) STEPP(0x142, 0xA) STEPP(0x143, 0xC)
#undef STEPP
    return __builtin_bit_cast(float,
        __builtin_amdgcn_readlane(__builtin_bit_cast(int, x), 63));
}

// Full-wave int max, result broadcast to all lanes.
__device__ __forceinline__ int wave_imax_bcast(int x) {
#define STEPM(CTRL, RM)                                                        \
    { int t_ = __builtin_amdgcn_update_dpp((int)0x80000000, x, CTRL, RM,       \
                                           0xF, false);                        \
      x = (x > t_) ? x : t_; }
    STEPM(0x111, 0xF) STEPM(0x112, 0xF) STEPM(0x114, 0xF)
    STEPM(0x118, 0xF) STEPM(0x142, 0xA) STEPM(0x143, 0xC)
#undef STEPM
    return __builtin_amdgcn_readlane(x, 63);
}

__global__ void __launch_bounds__(256)
fused_alpha_weights(const float* __restrict__ density,
                    const int*   __restrict__ ray_id,
                    const float* __restrict__ shift_p,
                    const float* __restrict__ interval_p,
                    float* __restrict__ weights,
                    float* __restrict__ alphainv,
                    int n_pts, int n_rays) {
    const int t    = threadIdx.x;
    const int lane = t & 63;
    const int wid  = t >> 6;

    // XCD-aware bijective swizzle (m204): XCD k owns a contiguous data chunk,
    // so data-neighbor blocks are consecutive launches on the SAME XCD.
    const int nwg  = gridDim.x;
    const int orig = blockIdx.x;
    const int qq   = nwg / NXCD, rr = nwg % NXCD;
    const int xcd  = orig % NXCD;
    const int blk  = (xcd < rr ? xcd * (qq + 1) : rr * (qq + 1) + (xcd - rr) * qq)
                   + orig / NXCD;

    const int wbase = blk * BPTS + wid * WSPAN;   // this wave's span start
    if (wbase >= n_pts) return;                   // legal: no barriers anywhere
    const int idx0  = wbase + lane * EPT;

    const float shift = shift_p[0];
    const float c     = interval_p[0];
    const float sh2   = shift * LOG2E;
    const float negc  = -c;
    const bool  fast  = (c == 0.5f);

    // ================= phase 0: issue ALL loads up front =================
    int r[EPT + 1]; float d[EPT]; bool v[EPT];
    if (idx0 + EPT <= n_pts) {
        const int4   ri0 = *reinterpret_cast<const int4*>(ray_id + idx0);
        const int4   ri1 = *reinterpret_cast<const int4*>(ray_id + idx0 + 4);
        const float4 de0 = *reinterpret_cast<const float4*>(density + idx0);
        const float4 de1 = *reinterpret_cast<const float4*>(density + idx0 + 4);
        r[0] = ri0.x; r[1] = ri0.y; r[2] = ri0.z; r[3] = ri0.w;
        r[4] = ri1.x; r[5] = ri1.y; r[6] = ri1.z; r[7] = ri1.w;
        d[0] = de0.x; d[1] = de0.y; d[2] = de0.z; d[3] = de0.w;
        d[4] = de1.x; d[5] = de1.y; d[6] = de1.z; d[7] = de1.w;
        #pragma unroll
        for (int k = 0; k < EPT; ++k) v[k] = true;
    } else {
        #pragma unroll
        for (int k = 0; k < EPT; ++k) {
            const int i = idx0 + k;
            v[k] = (i < n_pts);
            r[k] = v[k] ? ray_id[i] : n_rays;    // sentinel past-end ray
            d[k] = v[k] ? density[i] : 0.0f;
        }
    }

    // wave-boundary neighbor ids: only lanes 0/63 touch memory (L1-hot lines)
    int rprev_edge = -1;
    if (lane == 0 && idx0 > 0 && idx0 <= n_pts) rprev_edge = ray_id[idx0 - 1];
    int rnext_edge = n_rays;
    if (lane == 63 && idx0 + EPT < n_pts) rnext_edge = ray_id[idx0 + EPT];

    // this wave's lookback window: 4 elems/lane, coalesced, L1/L2-hot
    int   w_id[WPL]; float w_den[WPL];
    int   rfirst = 0;
    if (wbase > 0) {
        rfirst = ray_id[wbase];                  // uniform, cached
        #pragma unroll
        for (int j = 0; j < WPL; ++j) {
            const int wi = wbase - WIN + 64 * j + lane;
            w_id[j]  = ray_id[wi];
            w_den[j] = density[wi];
        }
    }

    // neighbor ray ids from adjacent lanes' registers (no strided gathers)
    const int rp_sh = __shfl_up(r[EPT - 1], 1, 64);
    const int rprev = (lane > 0) ? rp_sh : rprev_edge;
    const int rn_sh = __shfl_down(r[0], 1, 64);
    r[EPT] = (lane < 63) ? rn_sh : rnext_edge;

    // ================= phase 1: per-element values & flags =================
    float a[EPT]; int f[EPT];
    #pragma unroll
    for (int k = 0; k < EPT; ++k) {
        const float av = oma(d[k], sh2, negc, fast);
        a[k] = v[k] ? av : 1.0f;
        f[k] = (k == 0) ? (r[0] != rprev) : (r[k] != r[k - 1]);
    }

    // thread-local (V,F) fold over EPT elements
    float V = a[0];  int F = f[0];
    #pragma unroll
    for (int k = 1; k < EPT; ++k) {
        V = f[k] ? a[k] : V * a[k];
        F |= f[k];
    }

    // wave64 inclusive segmented scan (DPP, VALU-only)
    float Vi = V;  int Fi = F;
    seg_step<0x111, 0xF>(Vi, Fi);   // row_shr:1
    seg_step<0x112, 0xF>(Vi, Fi);   // row_shr:2
    seg_step<0x114, 0xF>(Vi, Fi);   // row_shr:4
    seg_step<0x118, 0xF>(Vi, Fi);   // row_shr:8
    seg_step<0x142, 0xA>(Vi, Fi);   // row_bcast:15 -> rows 1,3
    seg_step<0x143, 0xC>(Vi, Fi);   // row_bcast:31 -> rows 2,3

    // ========== head carry: fully wave-local (no LDS, no barrier) ==========
    float carry0 = 1.0f;
    if (wbase > 0) {
        // find m = max window index whose id differs from rfirst (-1 if none)
        int cand = -1;
        #pragma unroll
        for (int j = 0; j < WPL; ++j)
            if (w_id[j] != rfirst) cand = 64 * j + lane;   // j ascending: max
        const int m = wave_imax_bcast(cand);

        // product over window indices > m
        float pp = 1.0f;
        #pragma unroll
        for (int j = 0; j < WPL; ++j) {
            const int i = 64 * j + lane;
            const float aa = oma(w_den[j], sh2, negc, fast);
            pp *= (i > m) ? aa : 1.0f;
        }
        carry0 = wave_prod_bcast(pp);

        if (m < 0) {                 // freak ray (head > WIN back): wave-local walk
            int lo = wbase - WIN;
            int mg = -1;
            while (mg < 0) {
                const int wstart = lo - WIN;
                int c2 = -1;
                float pw = 1.0f;
                #pragma unroll
                for (int j = 0; j < WPL; ++j) {
                    const int i = wstart + 64 * j + lane;
                    const int vv = (i >= 0) ? ray_id[i] : -1;    // i<0 differs
                    if (vv != rfirst) c2 = 64 * j + lane;
                }
                const int m2 = wave_imax_bcast(c2);
                #pragma unroll
                for (int j = 0; j < WPL; ++j) {
                    const int iw = 64 * j + lane;
                    const int i  = wstart + iw;
                    float aa = 1.0f;
                    if (iw > m2 && i >= 0) aa = oma(density[i], sh2, negc, fast);
                    pw *= aa;
                }
                carry0 *= wave_prod_bcast(pw);
                if (m2 >= 0) mg = 1; else lo = wstart;
            }
        }
    }

    // exclusive pair for this thread (within wave) + carry fold
    float Vx = __shfl_up(Vi, 1, 64);
    int   Fx = __shfl_up(Fi, 1, 64);
    if (lane == 0) { Vx = 1.0f; Fx = 0; }
    const float Ev = Fx ? Vx : carry0 * Vx;  // exclusive transmittance, elem 0

    // ================= phase 3: T chain, weights, alphainv =================
    float T[EPT], e[EPT];
    float prev = Ev;
    #pragma unroll
    for (int k = 0; k < EPT; ++k) {
        T[k] = f[k] ? 1.0f : prev;
        e[k] = T[k] * a[k];
        prev = e[k];
    }

    if (idx0 + EPT <= n_pts) {
        vf4 w0 = { T[0] - e[0], T[1] - e[1], T[2] - e[2], T[3] - e[3] };
        vf4 w1 = { T[4] - e[4], T[5] - e[5], T[6] - e[6], T[7] - e[7] };
        __builtin_nontemporal_store(w0, reinterpret_cast<vf4*>(weights + idx0));
        __builtin_nontemporal_store(w1, reinterpret_cast<vf4*>(weights + idx0 + 4));
    } else {
        #pragma unroll
        for (int k = 0; k < EPT; ++k)
            if (v[k]) weights[idx0 + k] = T[k] - e[k];
    }

    // segment ends: write alphainv for ending ray; fill empty rays in gaps
    #pragma unroll
    for (int k = 0; k < EPT; ++k) {
        if (v[k] && r[k] != r[k + 1]) {
            alphainv[r[k]] = e[k];
            for (int q = r[k] + 1; q < r[k + 1]; ++q) alphainv[q] = 1.0f;
        }
    }
    if (idx0 == 0) {                    // rays before the first point
        for (int q = 0; q < r[0]; ++q) alphainv[q] = 1.0f;
    }
}

extern "C" void kernel_launch(void* const* d_in, const int* in_sizes, int n_in,
                              void* d_out, int out_size, void* d_ws, size_t ws_size,
                              hipStream_t stream) {
    const float* density  = (const float*)d_in[0];
    const float* shift    = (const float*)d_in[1];   // 1-element array
    const float* interval = (const float*)d_in[2];   // 1-element array
    const int*   ray_id   = (const int*)d_in[3];
    const int n_pts  = in_sizes[0];
    const int n_rays = out_size - n_pts;

    float* weights  = (float*)d_out;              // [n_pts]
    float* alphainv = (float*)d_out + n_pts;      // [n_rays]

    const int grid = (n_pts + BPTS - 1) / BPTS;
    fused_alpha_weights<<<grid, 256, 0, stream>>>(
        density, ray_id, shift, interval, weights, alphainv, n_pts, n_rays);
}